// Round 10
// baseline (741.470 us; speedup 1.0000x reference)
//
#include <hip/hip_runtime.h>
#include <hip/hip_fp16.h>
#include <math.h>

#define NNODES 100000
#define NEDGES 3200000
#define NFEAT  512
#define NHID   256
#define NCLASS 40
#define DPB    128                       // dsts per bucket
#define NBUCK  782                       // ceil(NNODES / DPB)
#define TILE   16384                     // edges per bin block
#define NTILE  196                       // ceil(NEDGES / TILE)

typedef _Float16 half8 __attribute__((ext_vector_type(8)));
typedef _Float16 half4 __attribute__((ext_vector_type(4)));
typedef float  f32x4  __attribute__((ext_vector_type(4)));

// ============ W1 transpose + fp16 convert: W1[512][256] -> W1T[256][512] ====
__global__ __launch_bounds__(256) void w1_f16_kernel(
    const float* __restrict__ W1, _Float16* __restrict__ W1T)
{
    const int i = blockIdx.x * 256 + threadIdx.x;     // 131072 total
    if (i >= NFEAT * NHID) return;
    const int k = i >> 8;        // row of W1 (K)
    const int n = i & 255;       // col of W1 (N)
    W1T[n * NFEAT + k] = (_Float16)W1[i];
}

// ============ GEMM1 via f16 MFMA: h0 = fp16(x @ W1 + b1) ====================
// 128 rows x 256 cols per block; 4 waves, wave w owns cols w*64..+63.
// Per K-step (BK=32): 32 MFMAs/wave between one barrier pair.
__global__ __launch_bounds__(256) void gemm1_f16_kernel(
    const float* __restrict__ x, const _Float16* __restrict__ Bt,
    const float* __restrict__ b1, _Float16* __restrict__ h0)
{
    __shared__ __align__(16) _Float16 As[128 * 40];  // [row][k], pad 40
    const int t = threadIdx.x;
    const int lane = t & 63;
    const int w = t >> 6;
    const int row0 = blockIdx.x * 128;
    const int wn0 = w * 64;
    const int fr = lane & 15;
    const int fq = lane >> 4;
    const int srow = t >> 1;             // 0..127
    const int skq  = (t & 1) * 16;       // 0 or 16
    const int grow = row0 + srow;
    const float* xp = x + (size_t)grow * NFEAT + skq;
    _Float16* ap = &As[srow * 40 + skq];

    f32x4 acc[8][4] = {};

    for (int k0 = 0; k0 < NFEAT; k0 += 32) {
        // ---- load + convert A slice (16 floats -> fp16) ----
        half8 hv0, hv1;
        if (grow < NNODES) {
            const float4 u0 = *(const float4*)(xp + k0);
            const float4 u1 = *(const float4*)(xp + k0 + 4);
            const float4 u2 = *(const float4*)(xp + k0 + 8);
            const float4 u3 = *(const float4*)(xp + k0 + 12);
            hv0[0] = (_Float16)u0.x; hv0[1] = (_Float16)u0.y;
            hv0[2] = (_Float16)u0.z; hv0[3] = (_Float16)u0.w;
            hv0[4] = (_Float16)u1.x; hv0[5] = (_Float16)u1.y;
            hv0[6] = (_Float16)u1.z; hv0[7] = (_Float16)u1.w;
            hv1[0] = (_Float16)u2.x; hv1[1] = (_Float16)u2.y;
            hv1[2] = (_Float16)u2.z; hv1[3] = (_Float16)u2.w;
            hv1[4] = (_Float16)u3.x; hv1[5] = (_Float16)u3.y;
            hv1[6] = (_Float16)u3.z; hv1[7] = (_Float16)u3.w;
        } else {
            #pragma unroll
            for (int j = 0; j < 8; ++j) { hv0[j] = (_Float16)0.f; hv1[j] = (_Float16)0.f; }
        }
        __syncthreads();                 // prior iteration's frag reads done
        *(half8*)ap = hv0;
        *(half8*)(ap + 8) = hv1;
        __syncthreads();                 // LDS tile ready

        // ---- A frags from LDS ----
        half8 a_f[8];
        #pragma unroll
        for (int mt = 0; mt < 8; ++mt)
            a_f[mt] = *(const half8*)&As[(mt * 16 + fr) * 40 + fq * 8];
        // ---- B frags direct from global (256 KB, L2-hot) ----
        half8 b_f[4];
        #pragma unroll
        for (int nt = 0; nt < 4; ++nt) {
            const int n = wn0 + nt * 16 + fr;
            b_f[nt] = *(const half8*)(Bt + (size_t)n * NFEAT + k0 + fq * 8);
        }
        // ---- 32 MFMAs ----
        #pragma unroll
        for (int mt = 0; mt < 8; ++mt)
            #pragma unroll
            for (int nt = 0; nt < 4; ++nt)
                acc[mt][nt] = __builtin_amdgcn_mfma_f32_16x16x32_f16(
                    a_f[mt], b_f[nt], acc[mt][nt], 0, 0, 0);
    }
    // ---- epilogue: C/D layout col = lane&15, row = (lane>>4)*4 + r ----
    #pragma unroll
    for (int mt = 0; mt < 8; ++mt)
        #pragma unroll
        for (int nt = 0; nt < 4; ++nt) {
            const int c = wn0 + nt * 16 + fr;
            const float bias = b1[c];
            const int r0 = row0 + mt * 16 + fq * 4;
            #pragma unroll
            for (int r = 0; r < 4; ++r) {
                const int row = r0 + r;
                if (row < NNODES)
                    h0[(size_t)row * NHID + c] = (_Float16)(acc[mt][nt][r] + bias);
            }
        }
}

// ============ GEMM2: h2 = fp16(relu'd fp16 h1 @ W2 + b2) ====================
__global__ __launch_bounds__(256) void gemm2_kernel(
    const _Float16* __restrict__ h1, const float* __restrict__ W2,
    const float* __restrict__ b2, _Float16* __restrict__ h2)
{
    __shared__ float Bs[NHID * NCLASS];
    __shared__ float As[64][33];
    const int t = threadIdx.x;
    const int row0 = blockIdx.x * 64;
    for (int i = t; i < NHID * NCLASS; i += 256) Bs[i] = W2[i];
    const int r  = t & 63;
    const int cg = (t >> 6) * 10;
    const int am = t >> 2, ak = (t & 3) * 8;
    float acc[10] = {};
    for (int k0 = 0; k0 < NHID; k0 += 32) {
        __syncthreads();
        half8 hv;
        #pragma unroll
        for (int j = 0; j < 8; ++j) hv[j] = (_Float16)0.f;
        const int arow = row0 + am;
        if (arow < NNODES)
            hv = *(const half8*)(h1 + (size_t)arow * NHID + k0 + ak);
        #pragma unroll
        for (int j = 0; j < 8; ++j)
            As[am][ak + j] = (float)hv[j];
        __syncthreads();
        #pragma unroll
        for (int k = 0; k < 32; ++k) {
            const float a = As[r][k];
            #pragma unroll
            for (int j = 0; j < 10; ++j)
                acc[j] += a * Bs[(k0 + k) * NCLASS + cg + j];
        }
    }
    const int arow = row0 + r;
    if (arow < NNODES) {
        #pragma unroll
        for (int j = 0; j < 10; ++j)
            h2[(size_t)arow * NCLASS + cg + j] = (_Float16)(acc[j] + b2[cg + j]);
    }
}

// ============ CSR build: two-level binned counting sort =====================
__global__ __launch_bounds__(256) void csr_init_kernel(
    int* __restrict__ bhist, int* __restrict__ rowptr)
{
    const int i = blockIdx.x * 256 + threadIdx.x;
    if (i < NBUCK) bhist[i] = 0;
    if (i == 0) rowptr[NNODES] = NEDGES;
}

__global__ __launch_bounds__(256) void bin_count_kernel(
    const int* __restrict__ ei, int* __restrict__ bhist)
{
    __shared__ int h[NBUCK];
    const int t = threadIdx.x;
    for (int i = t; i < NBUCK; i += 256) h[i] = 0;
    __syncthreads();
    const int base = blockIdx.x * TILE;
    #pragma unroll 1
    for (int it = 0; it < TILE / 1024; ++it) {
        const int e = base + it * 1024 + t * 4;
        if (e + 3 < NEDGES) {
            const int4 d = *(const int4*)(ei + e);
            atomicAdd(&h[d.x >> 7], 1);
            atomicAdd(&h[d.y >> 7], 1);
            atomicAdd(&h[d.z >> 7], 1);
            atomicAdd(&h[d.w >> 7], 1);
        } else {
            for (int j = e; j < NEDGES; ++j) atomicAdd(&h[ei[j] >> 7], 1);
        }
    }
    __syncthreads();
    for (int i = t; i < NBUCK; i += 256)
        if (h[i]) atomicAdd(&bhist[i], h[i]);
}

__global__ __launch_bounds__(1024) void bucket_scan_kernel(
    const int* __restrict__ bhist, int* __restrict__ bbase, int* __restrict__ bcur)
{
    __shared__ int s[1024];
    const int t = threadIdx.x;
    const int v = (t < NBUCK) ? bhist[t] : 0;
    s[t] = v;
    __syncthreads();
    for (int o = 1; o < 1024; o <<= 1) {
        const int u = (t >= o) ? s[t - o] : 0;
        __syncthreads();
        s[t] += u;
        __syncthreads();
    }
    if (t < NBUCK) { bbase[t] = s[t] - v; bcur[t] = s[t] - v; }
    if (t == 1023) bbase[NBUCK] = s[1023];
}

// packed: .x = (local_dst << 17) | src
__global__ __launch_bounds__(256) void bin_scatter_kernel(
    const int* __restrict__ ei, const float* __restrict__ ew,
    int* __restrict__ bcur, int2* __restrict__ binned)
{
    __shared__ int h[NBUCK];
    __shared__ int cur[NBUCK];
    const int t = threadIdx.x;
    for (int i = t; i < NBUCK; i += 256) h[i] = 0;
    __syncthreads();
    const int base = blockIdx.x * TILE;
    #pragma unroll 1
    for (int it = 0; it < TILE / 1024; ++it) {
        const int e = base + it * 1024 + t * 4;
        if (e + 3 < NEDGES) {
            const int4 d = *(const int4*)(ei + e);
            atomicAdd(&h[d.x >> 7], 1);
            atomicAdd(&h[d.y >> 7], 1);
            atomicAdd(&h[d.z >> 7], 1);
            atomicAdd(&h[d.w >> 7], 1);
        } else {
            for (int j = e; j < NEDGES; ++j) atomicAdd(&h[ei[j] >> 7], 1);
        }
    }
    __syncthreads();
    for (int i = t; i < NBUCK; i += 256)
        if (h[i]) cur[i] = atomicAdd(&bcur[i], h[i]);
    __syncthreads();
    #pragma unroll 1
    for (int it = 0; it < TILE / 1024; ++it) {
        const int e = base + it * 1024 + t * 4;
        if (e + 3 < NEDGES) {
            const int4   d = *(const int4*)(ei + e);
            const int4   s = *(const int4*)(ei + NEDGES + e);
            const float4 w = *(const float4*)(ew + e);
            int p0 = atomicAdd(&cur[d.x >> 7], 1);
            int p1 = atomicAdd(&cur[d.y >> 7], 1);
            int p2 = atomicAdd(&cur[d.z >> 7], 1);
            int p3 = atomicAdd(&cur[d.w >> 7], 1);
            binned[p0] = make_int2(((d.x & 127) << 17) | s.x, __float_as_int(w.x));
            binned[p1] = make_int2(((d.y & 127) << 17) | s.y, __float_as_int(w.y));
            binned[p2] = make_int2(((d.z & 127) << 17) | s.z, __float_as_int(w.z));
            binned[p3] = make_int2(((d.w & 127) << 17) | s.w, __float_as_int(w.w));
        } else {
            for (int j = e; j < NEDGES; ++j) {
                const int dj = ei[j];
                const int p = atomicAdd(&cur[dj >> 7], 1);
                binned[p] = make_int2(((dj & 127) << 17) | ei[NEDGES + j],
                                      __float_as_int(ew[j]));
            }
        }
    }
}

// one block per bucket: exact dst-order pairs + rowptr (simple 128-key)
__global__ __launch_bounds__(256) void regroup_kernel(
    const int* __restrict__ bbase, const int2* __restrict__ binned,
    int* __restrict__ rowptr, int2* __restrict__ pairs)
{
    __shared__ int cnt[DPB];
    __shared__ int s[DPB];
    const int b = blockIdx.x;
    const int t = threadIdx.x;
    const int d0 = b * DPB;
    const int nd = (NNODES - d0 < DPB) ? (NNODES - d0) : DPB;
    if (t < DPB) cnt[t] = 0;
    __syncthreads();
    const int lo = bbase[b], hiE = bbase[b + 1];
    for (int idx = lo + t; idx < hiE; idx += 256)
        atomicAdd(&cnt[binned[idx].x >> 17], 1);
    __syncthreads();
    const int v = (t < DPB) ? cnt[t] : 0;
    if (t < DPB) s[t] = v;
    __syncthreads();
    for (int o = 1; o < DPB; o <<= 1) {
        const int u = (t >= o && t < DPB) ? s[t - o] : 0;
        __syncthreads();
        if (t < DPB) s[t] += u;
        __syncthreads();
    }
    if (t < nd) {
        const int base = lo + s[t] - v;
        rowptr[d0 + t] = base;
        cnt[t] = base;
    }
    __syncthreads();
    for (int idx = lo + t; idx < hiE; idx += 256) {
        const int2 e = binned[idx];
        const int l = e.x >> 17;
        const int pos = atomicAdd(&cnt[l], 1);
        pairs[pos] = make_int2(e.x & 0x1FFFF, e.y);
    }
}

// ============ SpMM1 full-row fp16 gather (+fused ReLU): wave per dst ========
__global__ __launch_bounds__(256) void spmm1_f16_kernel(
    const int* __restrict__ rowptr, const int2* __restrict__ pairs,
    const _Float16* __restrict__ h0, _Float16* __restrict__ h1)
{
    const int dst  = blockIdx.x * 4 + (threadIdx.x >> 6);
    const int lane = threadIdx.x & 63;
    if (dst >= NNODES) return;
    const int beg = rowptr[dst], end = rowptr[dst + 1];
    const _Float16* base = h0 + lane * 4;
    float a0[4] = {0.f, 0.f, 0.f, 0.f};
    float a1[4] = {0.f, 0.f, 0.f, 0.f};
    int j = beg;
    for (; j + 1 < end; j += 2) {
        const int2 p0 = pairs[j];
        const int2 p1 = pairs[j + 1];
        const half4 v0 = *(const half4*)(base + (size_t)p0.x * NHID);
        const half4 v1 = *(const half4*)(base + (size_t)p1.x * NHID);
        const float w0 = __int_as_float(p0.y), w1 = __int_as_float(p1.y);
        #pragma unroll
        for (int k = 0; k < 4; ++k) {
            a0[k] = fmaf((float)v0[k], w0, a0[k]);
            a1[k] = fmaf((float)v1[k], w1, a1[k]);
        }
    }
    if (j < end) {
        const int2 p0 = pairs[j];
        const half4 v0 = *(const half4*)(base + (size_t)p0.x * NHID);
        const float w0 = __int_as_float(p0.y);
        #pragma unroll
        for (int k = 0; k < 4; ++k)
            a0[k] = fmaf((float)v0[k], w0, a0[k]);
    }
    half4 o;
    o[0] = (_Float16)fmaxf(a0[0] + a1[0], 0.f);
    o[1] = (_Float16)fmaxf(a0[1] + a1[1], 0.f);
    o[2] = (_Float16)fmaxf(a0[2] + a1[2], 0.f);
    o[3] = (_Float16)fmaxf(a0[3] + a1[3], 0.f);
    *(half4*)(h1 + (size_t)dst * NHID + lane * 4) = o;
}

// ============ SpMM2 (fp16 gather) + fused log-softmax: wave per dst =========
__global__ __launch_bounds__(256) void spmm2_csr_kernel(
    const int* __restrict__ rowptr, const int2* __restrict__ pairs,
    const _Float16* __restrict__ h2, float* __restrict__ out)
{
    const int dst  = blockIdx.x * 4 + (threadIdx.x >> 6);
    const int lane = threadIdx.x & 63;
    if (dst >= NNODES) return;
    const int beg = rowptr[dst], end = rowptr[dst + 1];
    float a0 = 0.f, a1 = 0.f;
    int j = beg;
    for (; j + 1 < end; j += 2) {
        const int2 p0 = pairs[j];
        const int2 p1 = pairs[j + 1];
        float v0 = 0.f, v1 = 0.f;
        if (lane < NCLASS) {
            v0 = (float)h2[(size_t)p0.x * NCLASS + lane];
            v1 = (float)h2[(size_t)p1.x * NCLASS + lane];
        }
        a0 = fmaf(v0, __int_as_float(p0.y), a0);
        a1 = fmaf(v1, __int_as_float(p1.y), a1);
    }
    if (j < end) {
        const int2 p0 = pairs[j];
        float v0 = 0.f;
        if (lane < NCLASS) v0 = (float)h2[(size_t)p0.x * NCLASS + lane];
        a0 = fmaf(v0, __int_as_float(p0.y), a0);
    }
    const float acc = a0 + a1;
    float val = (lane < NCLASS) ? acc : -INFINITY;
    float m = val;
    #pragma unroll
    for (int o = 32; o >= 1; o >>= 1) m = fmaxf(m, __shfl_xor(m, o));
    float ex = (lane < NCLASS) ? expf(val - m) : 0.f;
    float s = ex;
    #pragma unroll
    for (int o = 32; o >= 1; o >>= 1) s += __shfl_xor(s, o);
    if (lane < NCLASS) out[(size_t)dst * NCLASS + lane] = val - m - logf(s);
}

// ============ launch ========================================================
extern "C" void kernel_launch(void* const* d_in, const int* in_sizes, int n_in,
                              void* d_out, int out_size, void* d_ws, size_t ws_size,
                              hipStream_t stream)
{
    const float* x  = (const float*)d_in[0];
    const int*   ei = (const int*)d_in[1];   // [2,E]: dst row then src row
    const float* ew = (const float*)d_in[2];
    const float* W1 = (const float*)d_in[3];
    const float* b1 = (const float*)d_in[4];
    const float* W2 = (const float*)d_in[5];
    const float* b2 = (const float*)d_in[6];
    float* out = (float*)d_out;

    char* ws = (char*)d_ws;
    const size_t H_BYTES = (size_t)NNODES * NHID * 4;        // 102,400,000
    _Float16* h0 = (_Float16*)(ws);          // 51.2 MB fp16
    _Float16* h1 = (_Float16*)(ws + H_BYTES);// 51.2 MB fp16
    int2* binned = (int2*)(ws + H_BYTES);    // aliases h1 (dead before spmm1)
    int2* pairs  = (int2*)(ws + 2 * H_BYTES);                // 25.6 MB
    char* region = ws + 2 * H_BYTES + (size_t)NEDGES * 8;
    // W1T (256 KB) dead after gemm1; CSR arrays occupy the same bytes after.
    _Float16* W1T = (_Float16*)(region);                     // 262,144 B
    int* rowptr = (int*)(region);                            // 400,016 B
    int* bhist  = (int*)(region + 400016);                   // 3,128 B
    int* bbase  = (int*)(region + 403152);                   // 3,132 B
    int* bcur   = (int*)(region + 406288);                   // 3,128 B
    _Float16* h2 = (_Float16*)(ws);    // 8 MB fp16, aliases h0 (dead after spmm1)

    // 1. W1 -> transposed fp16; h0 = fp16(x @ W1 + b1), 128x256 MFMA tile
    w1_f16_kernel<<<(NFEAT * NHID + 255) / 256, 256, 0, stream>>>(W1, W1T);
    gemm1_f16_kernel<<<(NNODES + 127) / 128, 256, 0, stream>>>(x, W1T, b1, h0);
    // 2. CSR build: binned counting sort (W1T dead from here)
    csr_init_kernel<<<(NBUCK + 255) / 256, 256, 0, stream>>>(bhist, rowptr);
    bin_count_kernel<<<NTILE, 256, 0, stream>>>(ei, bhist);
    bucket_scan_kernel<<<1, 1024, 0, stream>>>(bhist, bbase, bcur);
    bin_scatter_kernel<<<NTILE, 256, 0, stream>>>(ei, ew, bcur, binned);
    regroup_kernel<<<NBUCK, 256, 0, stream>>>(bbase, binned, rowptr, pairs);
    // 3. h1 = fp16(relu(spmm(h0))) — full-row gather, wave per dst
    spmm1_f16_kernel<<<(NNODES + 3) / 4, 256, 0, stream>>>(rowptr, pairs, h0, h1);
    // 4. h2 = fp16(h1 @ W2 + b2)
    gemm2_kernel<<<(NNODES + 63) / 64, 256, 0, stream>>>(h1, W2, b2, h2);
    // 5. out = logsoftmax(spmm(h2)) — fp16 gather
    spmm2_csr_kernel<<<(NNODES + 3) / 4, 256, 0, stream>>>(rowptr, pairs, h2, out);
}

// Round 11
// 703.525 us; speedup vs baseline: 1.0539x; 1.0539x over previous
//
#include <hip/hip_runtime.h>
#include <hip/hip_fp16.h>
#include <math.h>

#define NNODES 100000
#define NEDGES 3200000
#define NFEAT  512
#define NHID   256
#define NCLASS 40
#define DPB    128                       // dsts per bucket
#define NBUCK  782                       // ceil(NNODES / DPB)
#define TILE   16384                     // edges per bin block
#define NTILE  196                       // ceil(NEDGES / TILE)

typedef _Float16 half8 __attribute__((ext_vector_type(8)));
typedef _Float16 half4 __attribute__((ext_vector_type(4)));
typedef float  f32x4  __attribute__((ext_vector_type(4)));

// ============ fused: W1 -> W1T fp16  +  CSR init ===========================
__global__ __launch_bounds__(256) void w1_init_kernel(
    const float* __restrict__ W1, _Float16* __restrict__ W1T,
    int* __restrict__ bhist, int* __restrict__ rowptr)
{
    const int i = blockIdx.x * 256 + threadIdx.x;     // 131072 total
    if (i < NFEAT * NHID) {
        const int k = i >> 8;        // row of W1 (K)
        const int n = i & 255;       // col of W1 (N)
        W1T[n * NFEAT + k] = (_Float16)W1[i];
    }
    if (i < NBUCK) bhist[i] = 0;
    if (i == 0) rowptr[NNODES] = NEDGES;
}

// ============ GEMM1 via f16 MFMA (single pass): h0 = fp16(x @ W1 + b1) ======
// block = 256 thr = 4 waves; tile 64 rows x 256 cols; wave w owns cols w*64..+63
__global__ __launch_bounds__(256) void gemm1_f16_kernel(
    const float* __restrict__ x, const _Float16* __restrict__ Bt,
    const float* __restrict__ b1, _Float16* __restrict__ h0)
{
    __shared__ __align__(16) _Float16 As[64 * 40];   // [row][k], pad 40
    const int t = threadIdx.x;
    const int lane = t & 63;
    const int w = t >> 6;
    const int row0 = blockIdx.x * 64;
    const int wn0 = w * 64;
    const int fr = lane & 15;
    const int fq = lane >> 4;
    const int srow = t >> 2;
    const int skq  = (t & 3) * 8;
    const int grow = row0 + srow;
    const float* xp = x + (size_t)grow * NFEAT + skq;
    _Float16* ap = &As[srow * 40 + skq];

    f32x4 acc[4][4] = {};

    for (int k0 = 0; k0 < NFEAT; k0 += 32) {
        half8 hv;
        if (grow < NNODES) {
            const float4 u0 = *(const float4*)(xp + k0);
            const float4 u1 = *(const float4*)(xp + k0 + 4);
            hv[0] = (_Float16)u0.x; hv[1] = (_Float16)u0.y;
            hv[2] = (_Float16)u0.z; hv[3] = (_Float16)u0.w;
            hv[4] = (_Float16)u1.x; hv[5] = (_Float16)u1.y;
            hv[6] = (_Float16)u1.z; hv[7] = (_Float16)u1.w;
        } else {
            #pragma unroll
            for (int j = 0; j < 8; ++j) hv[j] = (_Float16)0.f;
        }
        __syncthreads();
        *(half8*)ap = hv;
        __syncthreads();

        half8 a_f[4];
        #pragma unroll
        for (int mt = 0; mt < 4; ++mt)
            a_f[mt] = *(const half8*)&As[(mt * 16 + fr) * 40 + fq * 8];
        half8 b_f[4];
        #pragma unroll
        for (int nt = 0; nt < 4; ++nt) {
            const int n = wn0 + nt * 16 + fr;
            b_f[nt] = *(const half8*)(Bt + (size_t)n * NFEAT + k0 + fq * 8);
        }
        #pragma unroll
        for (int mt = 0; mt < 4; ++mt)
            #pragma unroll
            for (int nt = 0; nt < 4; ++nt)
                acc[mt][nt] = __builtin_amdgcn_mfma_f32_16x16x32_f16(
                    a_f[mt], b_f[nt], acc[mt][nt], 0, 0, 0);
    }
    #pragma unroll
    for (int mt = 0; mt < 4; ++mt)
        #pragma unroll
        for (int nt = 0; nt < 4; ++nt) {
            const int c = wn0 + nt * 16 + fr;
            const float bias = b1[c];
            const int r0 = row0 + mt * 16 + fq * 4;
            #pragma unroll
            for (int r = 0; r < 4; ++r) {
                const int row = r0 + r;
                if (row < NNODES)
                    h0[(size_t)row * NHID + c] = (_Float16)(acc[mt][nt][r] + bias);
            }
        }
}

// ============ GEMM2: h2 = fp16(relu'd fp16 h1 @ W2 + b2) ====================
__global__ __launch_bounds__(256) void gemm2_kernel(
    const _Float16* __restrict__ h1, const float* __restrict__ W2,
    const float* __restrict__ b2, _Float16* __restrict__ h2)
{
    __shared__ float Bs[NHID * NCLASS];
    __shared__ float As[64][33];
    const int t = threadIdx.x;
    const int row0 = blockIdx.x * 64;
    for (int i = t; i < NHID * NCLASS; i += 256) Bs[i] = W2[i];
    const int r  = t & 63;
    const int cg = (t >> 6) * 10;
    const int am = t >> 2, ak = (t & 3) * 8;
    float acc[10] = {};
    for (int k0 = 0; k0 < NHID; k0 += 32) {
        __syncthreads();
        half8 hv;
        #pragma unroll
        for (int j = 0; j < 8; ++j) hv[j] = (_Float16)0.f;
        const int arow = row0 + am;
        if (arow < NNODES)
            hv = *(const half8*)(h1 + (size_t)arow * NHID + k0 + ak);
        #pragma unroll
        for (int j = 0; j < 8; ++j)
            As[am][ak + j] = (float)hv[j];
        __syncthreads();
        #pragma unroll
        for (int k = 0; k < 32; ++k) {
            const float a = As[r][k];
            #pragma unroll
            for (int j = 0; j < 10; ++j)
                acc[j] += a * Bs[(k0 + k) * NCLASS + cg + j];
        }
    }
    const int arow = row0 + r;
    if (arow < NNODES) {
        #pragma unroll
        for (int j = 0; j < 10; ++j)
            h2[(size_t)arow * NCLASS + cg + j] = (_Float16)(acc[j] + b2[cg + j]);
    }
}

// ============ CSR build: two-level binned counting sort =====================
__global__ __launch_bounds__(256) void bin_count_kernel(
    const int* __restrict__ ei, int* __restrict__ bhist)
{
    __shared__ int h[NBUCK];
    const int t = threadIdx.x;
    for (int i = t; i < NBUCK; i += 256) h[i] = 0;
    __syncthreads();
    const int base = blockIdx.x * TILE;
    #pragma unroll 1
    for (int it = 0; it < TILE / 1024; ++it) {
        const int e = base + it * 1024 + t * 4;
        if (e + 3 < NEDGES) {
            const int4 d = *(const int4*)(ei + e);
            atomicAdd(&h[d.x >> 7], 1);
            atomicAdd(&h[d.y >> 7], 1);
            atomicAdd(&h[d.z >> 7], 1);
            atomicAdd(&h[d.w >> 7], 1);
        } else {
            for (int j = e; j < NEDGES; ++j) atomicAdd(&h[ei[j] >> 7], 1);
        }
    }
    __syncthreads();
    for (int i = t; i < NBUCK; i += 256)
        if (h[i]) atomicAdd(&bhist[i], h[i]);
}

__global__ __launch_bounds__(1024) void bucket_scan_kernel(
    const int* __restrict__ bhist, int* __restrict__ bbase, int* __restrict__ bcur)
{
    __shared__ int s[1024];
    const int t = threadIdx.x;
    const int v = (t < NBUCK) ? bhist[t] : 0;
    s[t] = v;
    __syncthreads();
    for (int o = 1; o < 1024; o <<= 1) {
        const int u = (t >= o) ? s[t - o] : 0;
        __syncthreads();
        s[t] += u;
        __syncthreads();
    }
    if (t < NBUCK) { bbase[t] = s[t] - v; bcur[t] = s[t] - v; }
    if (t == 1023) bbase[NBUCK] = s[1023];
}

// packed: .x = (local_dst << 17) | src
__global__ __launch_bounds__(256) void bin_scatter_kernel(
    const int* __restrict__ ei, const float* __restrict__ ew,
    int* __restrict__ bcur, int2* __restrict__ binned)
{
    __shared__ int h[NBUCK];
    __shared__ int cur[NBUCK];
    const int t = threadIdx.x;
    for (int i = t; i < NBUCK; i += 256) h[i] = 0;
    __syncthreads();
    const int base = blockIdx.x * TILE;
    #pragma unroll 1
    for (int it = 0; it < TILE / 1024; ++it) {
        const int e = base + it * 1024 + t * 4;
        if (e + 3 < NEDGES) {
            const int4 d = *(const int4*)(ei + e);
            atomicAdd(&h[d.x >> 7], 1);
            atomicAdd(&h[d.y >> 7], 1);
            atomicAdd(&h[d.z >> 7], 1);
            atomicAdd(&h[d.w >> 7], 1);
        } else {
            for (int j = e; j < NEDGES; ++j) atomicAdd(&h[ei[j] >> 7], 1);
        }
    }
    __syncthreads();
    for (int i = t; i < NBUCK; i += 256)
        if (h[i]) cur[i] = atomicAdd(&bcur[i], h[i]);
    __syncthreads();
    #pragma unroll 1
    for (int it = 0; it < TILE / 1024; ++it) {
        const int e = base + it * 1024 + t * 4;
        if (e + 3 < NEDGES) {
            const int4   d = *(const int4*)(ei + e);
            const int4   s = *(const int4*)(ei + NEDGES + e);
            const float4 w = *(const float4*)(ew + e);
            int p0 = atomicAdd(&cur[d.x >> 7], 1);
            int p1 = atomicAdd(&cur[d.y >> 7], 1);
            int p2 = atomicAdd(&cur[d.z >> 7], 1);
            int p3 = atomicAdd(&cur[d.w >> 7], 1);
            binned[p0] = make_int2(((d.x & 127) << 17) | s.x, __float_as_int(w.x));
            binned[p1] = make_int2(((d.y & 127) << 17) | s.y, __float_as_int(w.y));
            binned[p2] = make_int2(((d.z & 127) << 17) | s.z, __float_as_int(w.z));
            binned[p3] = make_int2(((d.w & 127) << 17) | s.w, __float_as_int(w.w));
        } else {
            for (int j = e; j < NEDGES; ++j) {
                const int dj = ei[j];
                const int p = atomicAdd(&cur[dj >> 7], 1);
                binned[p] = make_int2(((dj & 127) << 17) | ei[NEDGES + j],
                                      __float_as_int(ew[j]));
            }
        }
    }
}

// one block per bucket: exact dst-order pairs + rowptr (simple 128-key)
__global__ __launch_bounds__(256) void regroup_kernel(
    const int* __restrict__ bbase, const int2* __restrict__ binned,
    int* __restrict__ rowptr, int2* __restrict__ pairs)
{
    __shared__ int cnt[DPB];
    __shared__ int s[DPB];
    const int b = blockIdx.x;
    const int t = threadIdx.x;
    const int d0 = b * DPB;
    const int nd = (NNODES - d0 < DPB) ? (NNODES - d0) : DPB;
    if (t < DPB) cnt[t] = 0;
    __syncthreads();
    const int lo = bbase[b], hiE = bbase[b + 1];
    for (int idx = lo + t; idx < hiE; idx += 256)
        atomicAdd(&cnt[binned[idx].x >> 17], 1);
    __syncthreads();
    const int v = (t < DPB) ? cnt[t] : 0;
    if (t < DPB) s[t] = v;
    __syncthreads();
    for (int o = 1; o < DPB; o <<= 1) {
        const int u = (t >= o && t < DPB) ? s[t - o] : 0;
        __syncthreads();
        if (t < DPB) s[t] += u;
        __syncthreads();
    }
    if (t < nd) {
        const int base = lo + s[t] - v;
        rowptr[d0 + t] = base;
        cnt[t] = base;
    }
    __syncthreads();
    for (int idx = lo + t; idx < hiE; idx += 256) {
        const int2 e = binned[idx];
        const int l = e.x >> 17;
        const int pos = atomicAdd(&cnt[l], 1);
        pairs[pos] = make_int2(e.x & 0x1FFFF, e.y);
    }
}

// ============ SpMM1 full-row fp16 gather (+fused ReLU): wave per dst ========
__global__ __launch_bounds__(256) void spmm1_f16_kernel(
    const int* __restrict__ rowptr, const int2* __restrict__ pairs,
    const _Float16* __restrict__ h0, _Float16* __restrict__ h1)
{
    const int dst  = blockIdx.x * 4 + (threadIdx.x >> 6);
    const int lane = threadIdx.x & 63;
    if (dst >= NNODES) return;
    const int beg = rowptr[dst], end = rowptr[dst + 1];
    const _Float16* base = h0 + lane * 4;
    float a0[4] = {0.f, 0.f, 0.f, 0.f};
    float a1[4] = {0.f, 0.f, 0.f, 0.f};
    int j = beg;
    for (; j + 1 < end; j += 2) {
        const int2 p0 = pairs[j];
        const int2 p1 = pairs[j + 1];
        const half4 v0 = *(const half4*)(base + (size_t)p0.x * NHID);
        const half4 v1 = *(const half4*)(base + (size_t)p1.x * NHID);
        const float w0 = __int_as_float(p0.y), w1 = __int_as_float(p1.y);
        #pragma unroll
        for (int k = 0; k < 4; ++k) {
            a0[k] = fmaf((float)v0[k], w0, a0[k]);
            a1[k] = fmaf((float)v1[k], w1, a1[k]);
        }
    }
    if (j < end) {
        const int2 p0 = pairs[j];
        const half4 v0 = *(const half4*)(base + (size_t)p0.x * NHID);
        const float w0 = __int_as_float(p0.y);
        #pragma unroll
        for (int k = 0; k < 4; ++k)
            a0[k] = fmaf((float)v0[k], w0, a0[k]);
    }
    half4 o;
    o[0] = (_Float16)fmaxf(a0[0] + a1[0], 0.f);
    o[1] = (_Float16)fmaxf(a0[1] + a1[1], 0.f);
    o[2] = (_Float16)fmaxf(a0[2] + a1[2], 0.f);
    o[3] = (_Float16)fmaxf(a0[3] + a1[3], 0.f);
    *(half4*)(h1 + (size_t)dst * NHID + lane * 4) = o;
}

// ============ SpMM2 (fp16 gather) + fused log-softmax: wave per dst =========
__global__ __launch_bounds__(256) void spmm2_csr_kernel(
    const int* __restrict__ rowptr, const int2* __restrict__ pairs,
    const _Float16* __restrict__ h2, float* __restrict__ out)
{
    const int dst  = blockIdx.x * 4 + (threadIdx.x >> 6);
    const int lane = threadIdx.x & 63;
    if (dst >= NNODES) return;
    const int beg = rowptr[dst], end = rowptr[dst + 1];
    float a0 = 0.f, a1 = 0.f;
    int j = beg;
    for (; j + 1 < end; j += 2) {
        const int2 p0 = pairs[j];
        const int2 p1 = pairs[j + 1];
        float v0 = 0.f, v1 = 0.f;
        if (lane < NCLASS) {
            v0 = (float)h2[(size_t)p0.x * NCLASS + lane];
            v1 = (float)h2[(size_t)p1.x * NCLASS + lane];
        }
        a0 = fmaf(v0, __int_as_float(p0.y), a0);
        a1 = fmaf(v1, __int_as_float(p1.y), a1);
    }
    if (j < end) {
        const int2 p0 = pairs[j];
        float v0 = 0.f;
        if (lane < NCLASS) v0 = (float)h2[(size_t)p0.x * NCLASS + lane];
        a0 = fmaf(v0, __int_as_float(p0.y), a0);
    }
    const float acc = a0 + a1;
    float val = (lane < NCLASS) ? acc : -INFINITY;
    float m = val;
    #pragma unroll
    for (int o = 32; o >= 1; o >>= 1) m = fmaxf(m, __shfl_xor(m, o));
    float ex = (lane < NCLASS) ? expf(val - m) : 0.f;
    float s = ex;
    #pragma unroll
    for (int o = 32; o >= 1; o >>= 1) s += __shfl_xor(s, o);
    if (lane < NCLASS) out[(size_t)dst * NCLASS + lane] = val - m - logf(s);
}

// ============ launch ========================================================
extern "C" void kernel_launch(void* const* d_in, const int* in_sizes, int n_in,
                              void* d_out, int out_size, void* d_ws, size_t ws_size,
                              hipStream_t stream)
{
    const float* x  = (const float*)d_in[0];
    const int*   ei = (const int*)d_in[1];   // [2,E]: dst row then src row
    const float* ew = (const float*)d_in[2];
    const float* W1 = (const float*)d_in[3];
    const float* b1 = (const float*)d_in[4];
    const float* W2 = (const float*)d_in[5];
    const float* b2 = (const float*)d_in[6];
    float* out = (float*)d_out;

    char* ws = (char*)d_ws;
    const size_t H_BYTES = (size_t)NNODES * NHID * 4;        // 102,400,000
    _Float16* h0 = (_Float16*)(ws);          // 51.2 MB fp16
    _Float16* h1 = (_Float16*)(ws + H_BYTES);// 51.2 MB fp16
    int2* binned = (int2*)(ws + H_BYTES);    // aliases h1 (dead before spmm1)
    int2* pairs  = (int2*)(ws + 2 * H_BYTES);                // 25.6 MB
    char* region = ws + 2 * H_BYTES + (size_t)NEDGES * 8;
    // W1T (256 KB) dead after gemm1; rowptr overwrites it afterwards.
    _Float16* W1T = (_Float16*)(region);                     // 262,144 B
    int* rowptr = (int*)(region);                            // 400,016 B
    int* bhist  = (int*)(region + 400016);                   // 3,128 B
    int* bbase  = (int*)(region + 403152);                   // 3,132 B
    int* bcur   = (int*)(region + 406288);                   // 3,128 B
    _Float16* h2 = (_Float16*)(ws);    // 8 MB fp16, aliases h0 (dead after spmm1)

    // NOTE: rowptr aliases W1T, but rowptr[NNODES] (byte 400000) is past W1T's
    // 262144 bytes, so w1_init's rowptr[NNODES]=E write survives gemm1.
    w1_init_kernel<<<(NFEAT * NHID + 255) / 256, 256, 0, stream>>>(W1, W1T, bhist, rowptr);
    // 1. h0 = fp16(x @ W1 + b1) — 64x256 MFMA tile (best measured)
    gemm1_f16_kernel<<<(NNODES + 63) / 64, 256, 0, stream>>>(x, W1T, b1, h0);
    // 2. CSR build: binned counting sort (W1T dead from here)
    bin_count_kernel<<<NTILE, 256, 0, stream>>>(ei, bhist);
    bucket_scan_kernel<<<1, 1024, 0, stream>>>(bhist, bbase, bcur);
    bin_scatter_kernel<<<NTILE, 256, 0, stream>>>(ei, ew, bcur, binned);
    regroup_kernel<<<NBUCK, 256, 0, stream>>>(bbase, binned, rowptr, pairs);
    // 3. h1 = fp16(relu(spmm(h0))) — full-row gather, wave per dst
    spmm1_f16_kernel<<<(NNODES + 3) / 4, 256, 0, stream>>>(rowptr, pairs, h0, h1);
    // 4. h2 = fp16(h1 @ W2 + b2)
    gemm2_kernel<<<(NNODES + 63) / 64, 256, 0, stream>>>(h1, W2, b2, h2);
    // 5. out = logsoftmax(spmm(h2)) — fp16 gather
    spmm2_csr_kernel<<<(NNODES + 3) / 4, 256, 0, stream>>>(rowptr, pairs, h2, out);
}

// Round 12
// 692.287 us; speedup vs baseline: 1.0710x; 1.0162x over previous
//
#include <hip/hip_runtime.h>
#include <hip/hip_fp16.h>
#include <math.h>

#define NNODES 100000
#define NEDGES 3200000
#define NFEAT  512
#define NHID   256
#define NCLASS 40
#define DPB    128                       // dsts per bucket
#define NBUCK  782                       // ceil(NNODES / DPB)
#define CAP    4608                      // bucket capacity (mean 4096, +8 sigma)
#define TILE   4096                      // edges per bin block
#define NTILE  782                       // ceil(NEDGES / TILE)

typedef _Float16 half8 __attribute__((ext_vector_type(8)));
typedef _Float16 half4 __attribute__((ext_vector_type(4)));
typedef float  f32x4  __attribute__((ext_vector_type(4)));

// ============ fused: W1 -> W1T fp16  +  bucket cursor init =================
__global__ __launch_bounds__(256) void w1_init_kernel(
    const float* __restrict__ W1, _Float16* __restrict__ W1T,
    int* __restrict__ bcur)
{
    const int i = blockIdx.x * 256 + threadIdx.x;     // 131072 total
    if (i < NFEAT * NHID) {
        const int k = i >> 8;        // row of W1 (K)
        const int n = i & 255;       // col of W1 (N)
        W1T[n * NFEAT + k] = (_Float16)W1[i];
    }
    if (i < NBUCK) bcur[i] = i * CAP;
}

// ============ GEMM1 via f16 MFMA (single pass): h0 = fp16(x @ W1 + b1) ======
// block = 256 thr = 4 waves; tile 64 rows x 256 cols; wave w owns cols w*64..+63
__global__ __launch_bounds__(256) void gemm1_f16_kernel(
    const float* __restrict__ x, const _Float16* __restrict__ Bt,
    const float* __restrict__ b1, _Float16* __restrict__ h0)
{
    __shared__ __align__(16) _Float16 As[64 * 40];   // [row][k], pad 40
    const int t = threadIdx.x;
    const int lane = t & 63;
    const int w = t >> 6;
    const int row0 = blockIdx.x * 64;
    const int wn0 = w * 64;
    const int fr = lane & 15;
    const int fq = lane >> 4;
    const int srow = t >> 2;
    const int skq  = (t & 3) * 8;
    const int grow = row0 + srow;
    const float* xp = x + (size_t)grow * NFEAT + skq;
    _Float16* ap = &As[srow * 40 + skq];

    f32x4 acc[4][4] = {};

    for (int k0 = 0; k0 < NFEAT; k0 += 32) {
        half8 hv;
        if (grow < NNODES) {
            const float4 u0 = *(const float4*)(xp + k0);
            const float4 u1 = *(const float4*)(xp + k0 + 4);
            hv[0] = (_Float16)u0.x; hv[1] = (_Float16)u0.y;
            hv[2] = (_Float16)u0.z; hv[3] = (_Float16)u0.w;
            hv[4] = (_Float16)u1.x; hv[5] = (_Float16)u1.y;
            hv[6] = (_Float16)u1.z; hv[7] = (_Float16)u1.w;
        } else {
            #pragma unroll
            for (int j = 0; j < 8; ++j) hv[j] = (_Float16)0.f;
        }
        __syncthreads();
        *(half8*)ap = hv;
        __syncthreads();

        half8 a_f[4];
        #pragma unroll
        for (int mt = 0; mt < 4; ++mt)
            a_f[mt] = *(const half8*)&As[(mt * 16 + fr) * 40 + fq * 8];
        half8 b_f[4];
        #pragma unroll
        for (int nt = 0; nt < 4; ++nt) {
            const int n = wn0 + nt * 16 + fr;
            b_f[nt] = *(const half8*)(Bt + (size_t)n * NFEAT + k0 + fq * 8);
        }
        #pragma unroll
        for (int mt = 0; mt < 4; ++mt)
            #pragma unroll
            for (int nt = 0; nt < 4; ++nt)
                acc[mt][nt] = __builtin_amdgcn_mfma_f32_16x16x32_f16(
                    a_f[mt], b_f[nt], acc[mt][nt], 0, 0, 0);
    }
    #pragma unroll
    for (int mt = 0; mt < 4; ++mt)
        #pragma unroll
        for (int nt = 0; nt < 4; ++nt) {
            const int c = wn0 + nt * 16 + fr;
            const float bias = b1[c];
            const int r0 = row0 + mt * 16 + fq * 4;
            #pragma unroll
            for (int r = 0; r < 4; ++r) {
                const int row = r0 + r;
                if (row < NNODES)
                    h0[(size_t)row * NHID + c] = (_Float16)(acc[mt][nt][r] + bias);
            }
        }
}

// ============ GEMM2: h2 = fp16(relu'd fp16 h1 @ W2 + b2) ====================
__global__ __launch_bounds__(256) void gemm2_kernel(
    const _Float16* __restrict__ h1, const float* __restrict__ W2,
    const float* __restrict__ b2, _Float16* __restrict__ h2)
{
    __shared__ float Bs[NHID * NCLASS];
    __shared__ float As[64][33];
    const int t = threadIdx.x;
    const int row0 = blockIdx.x * 64;
    for (int i = t; i < NHID * NCLASS; i += 256) Bs[i] = W2[i];
    const int r  = t & 63;
    const int cg = (t >> 6) * 10;
    const int am = t >> 2, ak = (t & 3) * 8;
    float acc[10] = {};
    for (int k0 = 0; k0 < NHID; k0 += 32) {
        __syncthreads();
        half8 hv;
        #pragma unroll
        for (int j = 0; j < 8; ++j) hv[j] = (_Float16)0.f;
        const int arow = row0 + am;
        if (arow < NNODES)
            hv = *(const half8*)(h1 + (size_t)arow * NHID + k0 + ak);
        #pragma unroll
        for (int j = 0; j < 8; ++j)
            As[am][ak + j] = (float)hv[j];
        __syncthreads();
        #pragma unroll
        for (int k = 0; k < 32; ++k) {
            const float a = As[r][k];
            #pragma unroll
            for (int j = 0; j < 10; ++j)
                acc[j] += a * Bs[(k0 + k) * NCLASS + cg + j];
        }
    }
    const int arow = row0 + r;
    if (arow < NNODES) {
        #pragma unroll
        for (int j = 0; j < 10; ++j)
            h2[(size_t)arow * NCLASS + cg + j] = (_Float16)(acc[j] + b2[cg + j]);
    }
}

// ============ bin_scatter: LDS hist -> reserve fixed-cap bucket range -> fill
// packed: .x = (local_dst << 17) | src
__global__ __launch_bounds__(256) void bin_scatter_kernel(
    const int* __restrict__ ei, const float* __restrict__ ew,
    int* __restrict__ bcur, int2* __restrict__ binned)
{
    __shared__ int h[NBUCK];
    __shared__ int cur[NBUCK];
    const int t = threadIdx.x;
    for (int i = t; i < NBUCK; i += 256) h[i] = 0;
    __syncthreads();
    const int base = blockIdx.x * TILE;
    #pragma unroll 1
    for (int it = 0; it < TILE / 1024; ++it) {
        const int e = base + it * 1024 + t * 4;
        if (e + 3 < NEDGES) {
            const int4 d = *(const int4*)(ei + e);
            atomicAdd(&h[d.x >> 7], 1);
            atomicAdd(&h[d.y >> 7], 1);
            atomicAdd(&h[d.z >> 7], 1);
            atomicAdd(&h[d.w >> 7], 1);
        } else {
            for (int j = e; j < NEDGES; ++j) atomicAdd(&h[ei[j] >> 7], 1);
        }
    }
    __syncthreads();
    for (int i = t; i < NBUCK; i += 256)
        if (h[i]) cur[i] = atomicAdd(&bcur[i], h[i]);
    __syncthreads();
    #pragma unroll 1
    for (int it = 0; it < TILE / 1024; ++it) {
        const int e = base + it * 1024 + t * 4;
        if (e + 3 < NEDGES) {
            const int4   d = *(const int4*)(ei + e);
            const int4   s = *(const int4*)(ei + NEDGES + e);
            const float4 w = *(const float4*)(ew + e);
            int p0 = atomicAdd(&cur[d.x >> 7], 1);
            int p1 = atomicAdd(&cur[d.y >> 7], 1);
            int p2 = atomicAdd(&cur[d.z >> 7], 1);
            int p3 = atomicAdd(&cur[d.w >> 7], 1);
            binned[p0] = make_int2(((d.x & 127) << 17) | s.x, __float_as_int(w.x));
            binned[p1] = make_int2(((d.y & 127) << 17) | s.y, __float_as_int(w.y));
            binned[p2] = make_int2(((d.z & 127) << 17) | s.z, __float_as_int(w.z));
            binned[p3] = make_int2(((d.w & 127) << 17) | s.w, __float_as_int(w.w));
        } else {
            for (int j = e; j < NEDGES; ++j) {
                const int dj = ei[j];
                const int p = atomicAdd(&cur[dj >> 7], 1);
                binned[p] = make_int2(((dj & 127) << 17) | ei[NEDGES + j],
                                      __float_as_int(ew[j]));
            }
        }
    }
}

// one block per bucket: count+scan 128 dsts -> rowbeg/rowend, dst-sorted pairs
__global__ __launch_bounds__(256) void regroup_kernel(
    const int* __restrict__ bend, const int2* __restrict__ binned,
    int* __restrict__ rowbeg, int* __restrict__ rowend, int2* __restrict__ pairs)
{
    __shared__ int cnt[DPB];
    __shared__ int s[DPB];
    const int b = blockIdx.x;
    const int t = threadIdx.x;
    const int d0 = b * DPB;
    const int nd = (NNODES - d0 < DPB) ? (NNODES - d0) : DPB;
    if (t < DPB) cnt[t] = 0;
    __syncthreads();
    const int lo = b * CAP, hiE = bend[b];
    for (int idx = lo + t; idx < hiE; idx += 256)
        atomicAdd(&cnt[binned[idx].x >> 17], 1);
    __syncthreads();
    const int v = (t < DPB) ? cnt[t] : 0;
    if (t < DPB) s[t] = v;
    __syncthreads();
    for (int o = 1; o < DPB; o <<= 1) {
        const int u = (t >= o && t < DPB) ? s[t - o] : 0;
        __syncthreads();
        if (t < DPB) s[t] += u;
        __syncthreads();
    }
    if (t < nd) {
        const int beg = lo + s[t] - v;
        rowbeg[d0 + t] = beg;
        rowend[d0 + t] = lo + s[t];
        cnt[t] = beg;                     // becomes cursor
    }
    __syncthreads();
    for (int idx = lo + t; idx < hiE; idx += 256) {
        const int2 e = binned[idx];
        const int l = e.x >> 17;
        const int pos = atomicAdd(&cnt[l], 1);
        pairs[pos] = make_int2(e.x & 0x1FFFF, e.y);
    }
}

// ============ SpMM1 full-row fp16 gather (+fused ReLU): wave per dst ========
__global__ __launch_bounds__(256) void spmm1_f16_kernel(
    const int* __restrict__ rowbeg, const int* __restrict__ rowend,
    const int2* __restrict__ pairs,
    const _Float16* __restrict__ h0, _Float16* __restrict__ h1)
{
    const int dst  = blockIdx.x * 4 + (threadIdx.x >> 6);
    const int lane = threadIdx.x & 63;
    if (dst >= NNODES) return;
    const int beg = rowbeg[dst], end = rowend[dst];
    const _Float16* base = h0 + lane * 4;
    float a0[4] = {0.f, 0.f, 0.f, 0.f};
    float a1[4] = {0.f, 0.f, 0.f, 0.f};
    int j = beg;
    for (; j + 1 < end; j += 2) {
        const int2 p0 = pairs[j];
        const int2 p1 = pairs[j + 1];
        const half4 v0 = *(const half4*)(base + (size_t)p0.x * NHID);
        const half4 v1 = *(const half4*)(base + (size_t)p1.x * NHID);
        const float w0 = __int_as_float(p0.y), w1 = __int_as_float(p1.y);
        #pragma unroll
        for (int k = 0; k < 4; ++k) {
            a0[k] = fmaf((float)v0[k], w0, a0[k]);
            a1[k] = fmaf((float)v1[k], w1, a1[k]);
        }
    }
    if (j < end) {
        const int2 p0 = pairs[j];
        const half4 v0 = *(const half4*)(base + (size_t)p0.x * NHID);
        const float w0 = __int_as_float(p0.y);
        #pragma unroll
        for (int k = 0; k < 4; ++k)
            a0[k] = fmaf((float)v0[k], w0, a0[k]);
    }
    half4 o;
    o[0] = (_Float16)fmaxf(a0[0] + a1[0], 0.f);
    o[1] = (_Float16)fmaxf(a0[1] + a1[1], 0.f);
    o[2] = (_Float16)fmaxf(a0[2] + a1[2], 0.f);
    o[3] = (_Float16)fmaxf(a0[3] + a1[3], 0.f);
    *(half4*)(h1 + (size_t)dst * NHID + lane * 4) = o;
}

// ============ SpMM2 (fp16 gather) + fused log-softmax: wave per dst =========
__global__ __launch_bounds__(256) void spmm2_csr_kernel(
    const int* __restrict__ rowbeg, const int* __restrict__ rowend,
    const int2* __restrict__ pairs,
    const _Float16* __restrict__ h2, float* __restrict__ out)
{
    const int dst  = blockIdx.x * 4 + (threadIdx.x >> 6);
    const int lane = threadIdx.x & 63;
    if (dst >= NNODES) return;
    const int beg = rowbeg[dst], end = rowend[dst];
    float a0 = 0.f, a1 = 0.f;
    int j = beg;
    for (; j + 1 < end; j += 2) {
        const int2 p0 = pairs[j];
        const int2 p1 = pairs[j + 1];
        float v0 = 0.f, v1 = 0.f;
        if (lane < NCLASS) {
            v0 = (float)h2[(size_t)p0.x * NCLASS + lane];
            v1 = (float)h2[(size_t)p1.x * NCLASS + lane];
        }
        a0 = fmaf(v0, __int_as_float(p0.y), a0);
        a1 = fmaf(v1, __int_as_float(p1.y), a1);
    }
    if (j < end) {
        const int2 p0 = pairs[j];
        float v0 = 0.f;
        if (lane < NCLASS) v0 = (float)h2[(size_t)p0.x * NCLASS + lane];
        a0 = fmaf(v0, __int_as_float(p0.y), a0);
    }
    const float acc = a0 + a1;
    float val = (lane < NCLASS) ? acc : -INFINITY;
    float m = val;
    #pragma unroll
    for (int o = 32; o >= 1; o >>= 1) m = fmaxf(m, __shfl_xor(m, o));
    float ex = (lane < NCLASS) ? expf(val - m) : 0.f;
    float s = ex;
    #pragma unroll
    for (int o = 32; o >= 1; o >>= 1) s += __shfl_xor(s, o);
    if (lane < NCLASS) out[(size_t)dst * NCLASS + lane] = val - m - logf(s);
}

// ============ launch ========================================================
extern "C" void kernel_launch(void* const* d_in, const int* in_sizes, int n_in,
                              void* d_out, int out_size, void* d_ws, size_t ws_size,
                              hipStream_t stream)
{
    const float* x  = (const float*)d_in[0];
    const int*   ei = (const int*)d_in[1];   // [2,E]: dst row then src row
    const float* ew = (const float*)d_in[2];
    const float* W1 = (const float*)d_in[3];
    const float* b1 = (const float*)d_in[4];
    const float* W2 = (const float*)d_in[5];
    const float* b2 = (const float*)d_in[6];
    float* out = (float*)d_out;

    char* ws = (char*)d_ws;
    const size_t H_BYTES = (size_t)NNODES * NHID * 4;        // 102,400,000
    // layout (total ~205.7 MB, well under proven 230.8):
    //   [0, 51.2M)        h0 fp16   (h2 fp16 8MB aliases base after spmm1)
    //   [51.2M, 80.1M)    pairs     (782*4608*8 = 28,827,648 B)
    //   [102.4M, 131.3M)  binned    (alias h1 slot; dead before spmm1)
    //   [102.4M, 153.6M)  h1 fp16
    //   [204.8M, ...)     W1T (dead after gemm1) / rowbeg, rowend, bcur
    _Float16* h0 = (_Float16*)(ws);
    int2* pairs  = (int2*)(ws + 51200000);
    _Float16* h1 = (_Float16*)(ws + H_BYTES);
    int2* binned = (int2*)(ws + H_BYTES);
    char* region = ws + 2 * H_BYTES;
    _Float16* W1T = (_Float16*)(region);                     // 262,144 B
    int* rowbeg = (int*)(region);                            // 400,000 B (alias W1T)
    int* rowend = (int*)(region + 400000);                   // 400,000 B
    int* bcur   = (int*)(region + 800000);                   // 3,128 B
    _Float16* h2 = (_Float16*)(ws);    // 8 MB fp16, aliases h0 (dead after spmm1)

    // 1. W1 -> W1T fp16 + bucket cursors; h0 = fp16(x @ W1 + b1)
    w1_init_kernel<<<(NFEAT * NHID + 255) / 256, 256, 0, stream>>>(W1, W1T, bcur);
    gemm1_f16_kernel<<<(NNODES + 63) / 64, 256, 0, stream>>>(x, W1T, b1, h0);
    // 2. CSR build: fixed-capacity bucket scatter + per-bucket regroup
    //    (no global count/scan kernels; W1T dead before rowbeg written)
    bin_scatter_kernel<<<NTILE, 256, 0, stream>>>(ei, ew, bcur, binned);
    regroup_kernel<<<NBUCK, 256, 0, stream>>>(bcur, binned, rowbeg, rowend, pairs);
    // 3. h1 = fp16(relu(spmm(h0))) — full-row gather, wave per dst
    spmm1_f16_kernel<<<(NNODES + 3) / 4, 256, 0, stream>>>(rowbeg, rowend, pairs, h0, h1);
    // 4. h2 = fp16(h1 @ W2 + b2)
    gemm2_kernel<<<(NNODES + 63) / 64, 256, 0, stream>>>(h1, W2, b2, h2);
    // 5. out = logsoftmax(spmm(h2)) — fp16 gather
    spmm2_csr_kernel<<<(NNODES + 3) / 4, 256, 0, stream>>>(rowbeg, rowend, pairs, h2, out);
}

// Round 13
// 639.266 us; speedup vs baseline: 1.1599x; 1.0829x over previous
//
#include <hip/hip_runtime.h>
#include <hip/hip_fp16.h>
#include <math.h>

#define NNODES 100000
#define NEDGES 3200000
#define NFEAT  512
#define NHID   256
#define NCLASS 40
#define DPB    128                       // dsts per bucket
#define NBUCK  782                       // ceil(NNODES / DPB)
#define CAP    4608                      // bucket capacity (mean 4096, +8 sigma)
#define TILE   4096                      // edges per bin block
#define NTILE  782                       // ceil(NEDGES / TILE)

typedef _Float16 half8 __attribute__((ext_vector_type(8)));
typedef _Float16 half4 __attribute__((ext_vector_type(4)));
typedef float  f32x4  __attribute__((ext_vector_type(4)));

// ====== fused init: W1 -> W1T fp16, W2 -> W2T fp16 [48][256], bucket cursors
__global__ __launch_bounds__(256) void w1_init_kernel(
    const float* __restrict__ W1, const float* __restrict__ W2,
    _Float16* __restrict__ W1T, _Float16* __restrict__ W2T,
    int* __restrict__ bcur)
{
    const int i = blockIdx.x * 256 + threadIdx.x;     // 131072 total
    if (i < NFEAT * NHID) {
        const int k = i >> 8;        // row of W1 (K)
        const int n = i & 255;       // col of W1 (N)
        W1T[n * NFEAT + k] = (_Float16)W1[i];
    }
    if (i < NHID * NCLASS) {         // W2 [256][40] -> W2T [48][256]
        const int k = i / NCLASS;
        const int n = i - k * NCLASS;
        W2T[n * NHID + k] = (_Float16)W2[i];
    } else if (i < NHID * NCLASS + 8 * NHID) {   // zero pad rows 40..47
        const int j = i - NHID * NCLASS;
        W2T[(NCLASS + (j >> 8)) * NHID + (j & 255)] = (_Float16)0.f;
    }
    if (i < NBUCK) bcur[i] = i * CAP;
}

// ============ GEMM1 via f16 MFMA (single pass): h0 = fp16(x @ W1 + b1) ======
// block = 256 thr = 4 waves; tile 64 rows x 256 cols; wave w owns cols w*64..+63
__global__ __launch_bounds__(256) void gemm1_f16_kernel(
    const float* __restrict__ x, const _Float16* __restrict__ Bt,
    const float* __restrict__ b1, _Float16* __restrict__ h0)
{
    __shared__ __align__(16) _Float16 As[64 * 40];   // [row][k], pad 40
    const int t = threadIdx.x;
    const int lane = t & 63;
    const int w = t >> 6;
    const int row0 = blockIdx.x * 64;
    const int wn0 = w * 64;
    const int fr = lane & 15;
    const int fq = lane >> 4;
    const int srow = t >> 2;
    const int skq  = (t & 3) * 8;
    const int grow = row0 + srow;
    const float* xp = x + (size_t)grow * NFEAT + skq;
    _Float16* ap = &As[srow * 40 + skq];

    f32x4 acc[4][4] = {};

    for (int k0 = 0; k0 < NFEAT; k0 += 32) {
        half8 hv;
        if (grow < NNODES) {
            const float4 u0 = *(const float4*)(xp + k0);
            const float4 u1 = *(const float4*)(xp + k0 + 4);
            hv[0] = (_Float16)u0.x; hv[1] = (_Float16)u0.y;
            hv[2] = (_Float16)u0.z; hv[3] = (_Float16)u0.w;
            hv[4] = (_Float16)u1.x; hv[5] = (_Float16)u1.y;
            hv[6] = (_Float16)u1.z; hv[7] = (_Float16)u1.w;
        } else {
            #pragma unroll
            for (int j = 0; j < 8; ++j) hv[j] = (_Float16)0.f;
        }
        __syncthreads();
        *(half8*)ap = hv;
        __syncthreads();

        half8 a_f[4];
        #pragma unroll
        for (int mt = 0; mt < 4; ++mt)
            a_f[mt] = *(const half8*)&As[(mt * 16 + fr) * 40 + fq * 8];
        half8 b_f[4];
        #pragma unroll
        for (int nt = 0; nt < 4; ++nt) {
            const int n = wn0 + nt * 16 + fr;
            b_f[nt] = *(const half8*)(Bt + (size_t)n * NFEAT + k0 + fq * 8);
        }
        #pragma unroll
        for (int mt = 0; mt < 4; ++mt)
            #pragma unroll
            for (int nt = 0; nt < 4; ++nt)
                acc[mt][nt] = __builtin_amdgcn_mfma_f32_16x16x32_f16(
                    a_f[mt], b_f[nt], acc[mt][nt], 0, 0, 0);
    }
    #pragma unroll
    for (int mt = 0; mt < 4; ++mt)
        #pragma unroll
        for (int nt = 0; nt < 4; ++nt) {
            const int c = wn0 + nt * 16 + fr;
            const float bias = b1[c];
            const int r0 = row0 + mt * 16 + fq * 4;
            #pragma unroll
            for (int r = 0; r < 4; ++r) {
                const int row = r0 + r;
                if (row < NNODES)
                    h0[(size_t)row * NHID + c] = (_Float16)(acc[mt][nt][r] + bias);
            }
        }
}

// ============ GEMM2 via f16 MFMA: h2 = fp16(h1 @ W2 + b2) ===================
// 64 rows/block; wave w owns rows w*16..+15; 3 col-tiles of 16 (40 used)
__global__ __launch_bounds__(256) void gemm2_mfma_kernel(
    const _Float16* __restrict__ h1, const _Float16* __restrict__ W2T,
    const float* __restrict__ b2, _Float16* __restrict__ h2)
{
    const int t = threadIdx.x;
    const int lane = t & 63;
    const int w = t >> 6;
    const int row0 = blockIdx.x * 64 + w * 16;
    const int fr = lane & 15;
    const int fq = lane >> 4;
    const int arow = row0 + fr;
    const _Float16* ap = h1 + (size_t)(arow < NNODES ? arow : 0) * NHID;

    f32x4 acc[3] = {};
    #pragma unroll
    for (int k0 = 0; k0 < NHID; k0 += 32) {
        const half8 a_f = *(const half8*)(ap + k0 + fq * 8);
        #pragma unroll
        for (int ct = 0; ct < 3; ++ct) {
            const half8 b_f = *(const half8*)(W2T + (ct * 16 + fr) * NHID + k0 + fq * 8);
            acc[ct] = __builtin_amdgcn_mfma_f32_16x16x32_f16(a_f, b_f, acc[ct], 0, 0, 0);
        }
    }
    #pragma unroll
    for (int ct = 0; ct < 3; ++ct) {
        const int n = ct * 16 + fr;
        if (n < NCLASS) {
            const float bias = b2[n];
            #pragma unroll
            for (int r = 0; r < 4; ++r) {
                const int row = row0 + fq * 4 + r;
                if (row < NNODES)
                    h2[(size_t)row * NCLASS + n] = (_Float16)(acc[ct][r] + bias);
            }
        }
    }
}

// ============ bin_scatter: LDS hist -> reserve fixed-cap bucket range -> fill
// packed: .x = (local_dst << 17) | src
__global__ __launch_bounds__(256) void bin_scatter_kernel(
    const int* __restrict__ ei, const float* __restrict__ ew,
    int* __restrict__ bcur, int2* __restrict__ binned)
{
    __shared__ int h[NBUCK];
    __shared__ int cur[NBUCK];
    const int t = threadIdx.x;
    for (int i = t; i < NBUCK; i += 256) h[i] = 0;
    __syncthreads();
    const int base = blockIdx.x * TILE;
    #pragma unroll 1
    for (int it = 0; it < TILE / 1024; ++it) {
        const int e = base + it * 1024 + t * 4;
        if (e + 3 < NEDGES) {
            const int4 d = *(const int4*)(ei + e);
            atomicAdd(&h[d.x >> 7], 1);
            atomicAdd(&h[d.y >> 7], 1);
            atomicAdd(&h[d.z >> 7], 1);
            atomicAdd(&h[d.w >> 7], 1);
        } else {
            for (int j = e; j < NEDGES; ++j) atomicAdd(&h[ei[j] >> 7], 1);
        }
    }
    __syncthreads();
    for (int i = t; i < NBUCK; i += 256)
        if (h[i]) cur[i] = atomicAdd(&bcur[i], h[i]);
    __syncthreads();
    #pragma unroll 1
    for (int it = 0; it < TILE / 1024; ++it) {
        const int e = base + it * 1024 + t * 4;
        if (e + 3 < NEDGES) {
            const int4   d = *(const int4*)(ei + e);
            const int4   s = *(const int4*)(ei + NEDGES + e);
            const float4 w = *(const float4*)(ew + e);
            int p0 = atomicAdd(&cur[d.x >> 7], 1);
            int p1 = atomicAdd(&cur[d.y >> 7], 1);
            int p2 = atomicAdd(&cur[d.z >> 7], 1);
            int p3 = atomicAdd(&cur[d.w >> 7], 1);
            binned[p0] = make_int2(((d.x & 127) << 17) | s.x, __float_as_int(w.x));
            binned[p1] = make_int2(((d.y & 127) << 17) | s.y, __float_as_int(w.y));
            binned[p2] = make_int2(((d.z & 127) << 17) | s.z, __float_as_int(w.z));
            binned[p3] = make_int2(((d.w & 127) << 17) | s.w, __float_as_int(w.w));
        } else {
            for (int j = e; j < NEDGES; ++j) {
                const int dj = ei[j];
                const int p = atomicAdd(&cur[dj >> 7], 1);
                binned[p] = make_int2(((dj & 127) << 17) | ei[NEDGES + j],
                                      __float_as_int(ew[j]));
            }
        }
    }
}

// one block per bucket: count+scan 128 dsts -> rowbeg/rowend, dst-sorted pairs
__global__ __launch_bounds__(256) void regroup_kernel(
    const int* __restrict__ bend, const int2* __restrict__ binned,
    int* __restrict__ rowbeg, int* __restrict__ rowend, int2* __restrict__ pairs)
{
    __shared__ int cnt[DPB];
    __shared__ int s[DPB];
    const int b = blockIdx.x;
    const int t = threadIdx.x;
    const int d0 = b * DPB;
    const int nd = (NNODES - d0 < DPB) ? (NNODES - d0) : DPB;
    if (t < DPB) cnt[t] = 0;
    __syncthreads();
    const int lo = b * CAP, hiE = bend[b];
    for (int idx = lo + t; idx < hiE; idx += 256)
        atomicAdd(&cnt[binned[idx].x >> 17], 1);
    __syncthreads();
    const int v = (t < DPB) ? cnt[t] : 0;
    if (t < DPB) s[t] = v;
    __syncthreads();
    for (int o = 1; o < DPB; o <<= 1) {
        const int u = (t >= o && t < DPB) ? s[t - o] : 0;
        __syncthreads();
        if (t < DPB) s[t] += u;
        __syncthreads();
    }
    if (t < nd) {
        const int beg = lo + s[t] - v;
        rowbeg[d0 + t] = beg;
        rowend[d0 + t] = lo + s[t];
        cnt[t] = beg;                     // becomes cursor
    }
    __syncthreads();
    for (int idx = lo + t; idx < hiE; idx += 256) {
        const int2 e = binned[idx];
        const int l = e.x >> 17;
        const int pos = atomicAdd(&cnt[l], 1);
        pairs[pos] = make_int2(e.x & 0x1FFFF, e.y);
    }
}

// ============ SpMM1 full-row fp16 gather (+fused ReLU): wave per dst ========
__global__ __launch_bounds__(256) void spmm1_f16_kernel(
    const int* __restrict__ rowbeg, const int* __restrict__ rowend,
    const int2* __restrict__ pairs,
    const _Float16* __restrict__ h0, _Float16* __restrict__ h1)
{
    const int dst  = blockIdx.x * 4 + (threadIdx.x >> 6);
    const int lane = threadIdx.x & 63;
    if (dst >= NNODES) return;
    const int beg = rowbeg[dst], end = rowend[dst];
    const _Float16* base = h0 + lane * 4;
    float a0[4] = {0.f, 0.f, 0.f, 0.f};
    float a1[4] = {0.f, 0.f, 0.f, 0.f};
    int j = beg;
    for (; j + 1 < end; j += 2) {
        const int2 p0 = pairs[j];
        const int2 p1 = pairs[j + 1];
        const half4 v0 = *(const half4*)(base + (size_t)p0.x * NHID);
        const half4 v1 = *(const half4*)(base + (size_t)p1.x * NHID);
        const float w0 = __int_as_float(p0.y), w1 = __int_as_float(p1.y);
        #pragma unroll
        for (int k = 0; k < 4; ++k) {
            a0[k] = fmaf((float)v0[k], w0, a0[k]);
            a1[k] = fmaf((float)v1[k], w1, a1[k]);
        }
    }
    if (j < end) {
        const int2 p0 = pairs[j];
        const half4 v0 = *(const half4*)(base + (size_t)p0.x * NHID);
        const float w0 = __int_as_float(p0.y);
        #pragma unroll
        for (int k = 0; k < 4; ++k)
            a0[k] = fmaf((float)v0[k], w0, a0[k]);
    }
    half4 o;
    o[0] = (_Float16)fmaxf(a0[0] + a1[0], 0.f);
    o[1] = (_Float16)fmaxf(a0[1] + a1[1], 0.f);
    o[2] = (_Float16)fmaxf(a0[2] + a1[2], 0.f);
    o[3] = (_Float16)fmaxf(a0[3] + a1[3], 0.f);
    *(half4*)(h1 + (size_t)dst * NHID + lane * 4) = o;
}

// ============ SpMM2 (fp16 gather) + fused log-softmax: wave per dst =========
__global__ __launch_bounds__(256) void spmm2_csr_kernel(
    const int* __restrict__ rowbeg, const int* __restrict__ rowend,
    const int2* __restrict__ pairs,
    const _Float16* __restrict__ h2, float* __restrict__ out)
{
    const int dst  = blockIdx.x * 4 + (threadIdx.x >> 6);
    const int lane = threadIdx.x & 63;
    if (dst >= NNODES) return;
    const int beg = rowbeg[dst], end = rowend[dst];
    float a0 = 0.f, a1 = 0.f;
    int j = beg;
    for (; j + 1 < end; j += 2) {
        const int2 p0 = pairs[j];
        const int2 p1 = pairs[j + 1];
        float v0 = 0.f, v1 = 0.f;
        if (lane < NCLASS) {
            v0 = (float)h2[(size_t)p0.x * NCLASS + lane];
            v1 = (float)h2[(size_t)p1.x * NCLASS + lane];
        }
        a0 = fmaf(v0, __int_as_float(p0.y), a0);
        a1 = fmaf(v1, __int_as_float(p1.y), a1);
    }
    if (j < end) {
        const int2 p0 = pairs[j];
        float v0 = 0.f;
        if (lane < NCLASS) v0 = (float)h2[(size_t)p0.x * NCLASS + lane];
        a0 = fmaf(v0, __int_as_float(p0.y), a0);
    }
    const float acc = a0 + a1;
    float val = (lane < NCLASS) ? acc : -INFINITY;
    float m = val;
    #pragma unroll
    for (int o = 32; o >= 1; o >>= 1) m = fmaxf(m, __shfl_xor(m, o));
    float ex = (lane < NCLASS) ? expf(val - m) : 0.f;
    float s = ex;
    #pragma unroll
    for (int o = 32; o >= 1; o >>= 1) s += __shfl_xor(s, o);
    if (lane < NCLASS) out[(size_t)dst * NCLASS + lane] = val - m - logf(s);
}

// ============ launch ========================================================
extern "C" void kernel_launch(void* const* d_in, const int* in_sizes, int n_in,
                              void* d_out, int out_size, void* d_ws, size_t ws_size,
                              hipStream_t stream)
{
    const float* x  = (const float*)d_in[0];
    const int*   ei = (const int*)d_in[1];   // [2,E]: dst row then src row
    const float* ew = (const float*)d_in[2];
    const float* W1 = (const float*)d_in[3];
    const float* b1 = (const float*)d_in[4];
    const float* W2 = (const float*)d_in[5];
    const float* b2 = (const float*)d_in[6];
    float* out = (float*)d_out;

    char* ws = (char*)d_ws;
    const size_t H_BYTES = (size_t)NNODES * NHID * 4;        // 102,400,000
    // layout (total ~205.7 MB, well under proven 230.8):
    //   [0, 51.2M)        h0 fp16   (h2 fp16 8MB aliases base after spmm1)
    //   [51.2M, 80.1M)    pairs     (782*4608*8 = 28,827,648 B)
    //   [102.4M, 131.3M)  binned    (alias h1 slot; dead before spmm1)
    //   [102.4M, 153.6M)  h1 fp16
    //   [204.8M, ...)     W1T (dead after gemm1) / rowbeg, rowend, bcur, W2T
    _Float16* h0 = (_Float16*)(ws);
    int2* pairs  = (int2*)(ws + 51200000);
    _Float16* h1 = (_Float16*)(ws + H_BYTES);
    int2* binned = (int2*)(ws + H_BYTES);
    char* region = ws + 2 * H_BYTES;
    _Float16* W1T = (_Float16*)(region);                     // 262,144 B
    int* rowbeg = (int*)(region);                            // 400,000 B (alias W1T)
    int* rowend = (int*)(region + 400000);                   // 400,000 B
    int* bcur   = (int*)(region + 800000);                   // 3,128 B
    _Float16* W2T = (_Float16*)(region + 803200);            // 24,576 B [48][256]
    _Float16* h2 = (_Float16*)(ws);    // 8 MB fp16, aliases h0 (dead after spmm1)

    // 1. W1T/W2T fp16 + bucket cursors; h0 = fp16(x @ W1 + b1)
    w1_init_kernel<<<(NFEAT * NHID + 255) / 256, 256, 0, stream>>>(W1, W2, W1T, W2T, bcur);
    gemm1_f16_kernel<<<(NNODES + 63) / 64, 256, 0, stream>>>(x, W1T, b1, h0);
    // 2. CSR build: fixed-capacity bucket scatter + per-bucket regroup
    bin_scatter_kernel<<<NTILE, 256, 0, stream>>>(ei, ew, bcur, binned);
    regroup_kernel<<<NBUCK, 256, 0, stream>>>(bcur, binned, rowbeg, rowend, pairs);
    // 3. h1 = fp16(relu(spmm(h0))) — full-row gather, wave per dst
    spmm1_f16_kernel<<<(NNODES + 3) / 4, 256, 0, stream>>>(rowbeg, rowend, pairs, h0, h1);
    // 4. h2 = fp16(h1 @ W2 + b2) — MFMA
    gemm2_mfma_kernel<<<(NNODES + 63) / 64, 256, 0, stream>>>(h1, W2T, b2, h2);
    // 5. out = logsoftmax(spmm(h2)) — fp16 gather
    spmm2_csr_kernel<<<(NNODES + 3) / 4, 256, 0, stream>>>(rowbeg, rowend, pairs, h2, out);
}

// Round 14
// 631.209 us; speedup vs baseline: 1.1747x; 1.0128x over previous
//
#include <hip/hip_runtime.h>
#include <hip/hip_fp16.h>
#include <math.h>

#define NNODES 100000
#define NEDGES 3200000
#define NFEAT  512
#define NHID   256
#define NCLASS 40
#define DPB    128                       // dsts per bucket
#define NBUCK  782                       // ceil(NNODES / DPB)
#define CAP    4608                      // bucket capacity (mean 4096, +8 sigma)
#define TILE   4096                      // edges per bin block
#define NTILE  782                       // ceil(NEDGES / TILE)

typedef _Float16 half8 __attribute__((ext_vector_type(8)));
typedef _Float16 half4 __attribute__((ext_vector_type(4)));
typedef float  f32x4  __attribute__((ext_vector_type(4)));

// ====== fused init: W1 -> W1T fp16, W2 -> W2T fp16 [48][256], bucket cursors
__global__ __launch_bounds__(256) void w1_init_kernel(
    const float* __restrict__ W1, const float* __restrict__ W2,
    _Float16* __restrict__ W1T, _Float16* __restrict__ W2T,
    int* __restrict__ bcur)
{
    const int i = blockIdx.x * 256 + threadIdx.x;     // 131072 total
    if (i < NFEAT * NHID) {
        const int k = i >> 8;        // row of W1 (K)
        const int n = i & 255;       // col of W1 (N)
        W1T[n * NFEAT + k] = (_Float16)W1[i];
    }
    if (i < NHID * NCLASS) {         // W2 [256][40] -> W2T [48][256]
        const int k = i / NCLASS;
        const int n = i - k * NCLASS;
        W2T[n * NHID + k] = (_Float16)W2[i];
    } else if (i < NHID * NCLASS + 8 * NHID) {   // zero pad rows 40..47
        const int j = i - NHID * NCLASS;
        W2T[(NCLASS + (j >> 8)) * NHID + (j & 255)] = (_Float16)0.f;
    }
    if (i < NBUCK) bcur[i] = i * CAP;
}

// ============ GEMM1 via f16 MFMA, BK=64: h0 = fp16(x @ W1 + b1) =============
// block = 256 thr = 4 waves; tile 64 rows x 256 cols; wave w owns cols w*64..+63
// 8 K-iterations, 32 MFMAs per wave between each barrier pair.
__global__ __launch_bounds__(256) void gemm1_f16_kernel(
    const float* __restrict__ x, const _Float16* __restrict__ Bt,
    const float* __restrict__ b1, _Float16* __restrict__ h0)
{
    __shared__ __align__(16) _Float16 As[64 * 72];   // [row][k], pad 64->72
    const int t = threadIdx.x;
    const int lane = t & 63;
    const int w = t >> 6;
    const int row0 = blockIdx.x * 64;
    const int wn0 = w * 64;
    const int fr = lane & 15;
    const int fq = lane >> 4;
    const int srow = t >> 2;             // 0..63
    const int skq  = (t & 3) * 16;       // 0,16,32,48
    const int grow = row0 + srow;
    const float* xp = x + (size_t)grow * NFEAT + skq;
    _Float16* ap = &As[srow * 72 + skq];

    f32x4 acc[4][4] = {};

    for (int k0 = 0; k0 < NFEAT; k0 += 64) {
        // ---- load + convert A slice (16 floats -> fp16) ----
        half8 hv0, hv1;
        if (grow < NNODES) {
            const float4 u0 = *(const float4*)(xp + k0);
            const float4 u1 = *(const float4*)(xp + k0 + 4);
            const float4 u2 = *(const float4*)(xp + k0 + 8);
            const float4 u3 = *(const float4*)(xp + k0 + 12);
            hv0[0] = (_Float16)u0.x; hv0[1] = (_Float16)u0.y;
            hv0[2] = (_Float16)u0.z; hv0[3] = (_Float16)u0.w;
            hv0[4] = (_Float16)u1.x; hv0[5] = (_Float16)u1.y;
            hv0[6] = (_Float16)u1.z; hv0[7] = (_Float16)u1.w;
            hv1[0] = (_Float16)u2.x; hv1[1] = (_Float16)u2.y;
            hv1[2] = (_Float16)u2.z; hv1[3] = (_Float16)u2.w;
            hv1[4] = (_Float16)u3.x; hv1[5] = (_Float16)u3.y;
            hv1[6] = (_Float16)u3.z; hv1[7] = (_Float16)u3.w;
        } else {
            #pragma unroll
            for (int j = 0; j < 8; ++j) { hv0[j] = (_Float16)0.f; hv1[j] = (_Float16)0.f; }
        }
        __syncthreads();                 // prior iteration's frag reads done
        *(half8*)ap = hv0;
        *(half8*)(ap + 8) = hv1;
        __syncthreads();                 // LDS tile ready

        #pragma unroll
        for (int ks = 0; ks < 2; ++ks) {
            half8 a_f[4];
            #pragma unroll
            for (int mt = 0; mt < 4; ++mt)
                a_f[mt] = *(const half8*)&As[(mt * 16 + fr) * 72 + ks * 32 + fq * 8];
            half8 b_f[4];
            #pragma unroll
            for (int nt = 0; nt < 4; ++nt) {
                const int n = wn0 + nt * 16 + fr;
                b_f[nt] = *(const half8*)(Bt + (size_t)n * NFEAT + k0 + ks * 32 + fq * 8);
            }
            #pragma unroll
            for (int mt = 0; mt < 4; ++mt)
                #pragma unroll
                for (int nt = 0; nt < 4; ++nt)
                    acc[mt][nt] = __builtin_amdgcn_mfma_f32_16x16x32_f16(
                        a_f[mt], b_f[nt], acc[mt][nt], 0, 0, 0);
        }
    }
    // ---- epilogue: C/D layout col = lane&15, row = (lane>>4)*4 + r ----
    #pragma unroll
    for (int mt = 0; mt < 4; ++mt)
        #pragma unroll
        for (int nt = 0; nt < 4; ++nt) {
            const int c = wn0 + nt * 16 + fr;
            const float bias = b1[c];
            const int r0 = row0 + mt * 16 + fq * 4;
            #pragma unroll
            for (int r = 0; r < 4; ++r) {
                const int row = r0 + r;
                if (row < NNODES)
                    h0[(size_t)row * NHID + c] = (_Float16)(acc[mt][nt][r] + bias);
            }
        }
}

// ============ GEMM2 via f16 MFMA: h2 = fp16(h1 @ W2 + b2) ===================
// 64 rows/block; wave w owns rows w*16..+15; 3 col-tiles of 16 (40 used)
__global__ __launch_bounds__(256) void gemm2_mfma_kernel(
    const _Float16* __restrict__ h1, const _Float16* __restrict__ W2T,
    const float* __restrict__ b2, _Float16* __restrict__ h2)
{
    const int t = threadIdx.x;
    const int lane = t & 63;
    const int w = t >> 6;
    const int row0 = blockIdx.x * 64 + w * 16;
    const int fr = lane & 15;
    const int fq = lane >> 4;
    const int arow = row0 + fr;
    const _Float16* ap = h1 + (size_t)(arow < NNODES ? arow : 0) * NHID;

    f32x4 acc[3] = {};
    #pragma unroll
    for (int k0 = 0; k0 < NHID; k0 += 32) {
        const half8 a_f = *(const half8*)(ap + k0 + fq * 8);
        #pragma unroll
        for (int ct = 0; ct < 3; ++ct) {
            const half8 b_f = *(const half8*)(W2T + (ct * 16 + fr) * NHID + k0 + fq * 8);
            acc[ct] = __builtin_amdgcn_mfma_f32_16x16x32_f16(a_f, b_f, acc[ct], 0, 0, 0);
        }
    }
    #pragma unroll
    for (int ct = 0; ct < 3; ++ct) {
        const int n = ct * 16 + fr;
        if (n < NCLASS) {
            const float bias = b2[n];
            #pragma unroll
            for (int r = 0; r < 4; ++r) {
                const int row = row0 + fq * 4 + r;
                if (row < NNODES)
                    h2[(size_t)row * NCLASS + n] = (_Float16)(acc[ct][r] + bias);
            }
        }
    }
}

// ============ bin_scatter: LDS hist -> reserve fixed-cap bucket range -> fill
// packed: .x = (local_dst << 17) | src
__global__ __launch_bounds__(256) void bin_scatter_kernel(
    const int* __restrict__ ei, const float* __restrict__ ew,
    int* __restrict__ bcur, int2* __restrict__ binned)
{
    __shared__ int h[NBUCK];
    __shared__ int cur[NBUCK];
    const int t = threadIdx.x;
    for (int i = t; i < NBUCK; i += 256) h[i] = 0;
    __syncthreads();
    const int base = blockIdx.x * TILE;
    #pragma unroll 1
    for (int it = 0; it < TILE / 1024; ++it) {
        const int e = base + it * 1024 + t * 4;
        if (e + 3 < NEDGES) {
            const int4 d = *(const int4*)(ei + e);
            atomicAdd(&h[d.x >> 7], 1);
            atomicAdd(&h[d.y >> 7], 1);
            atomicAdd(&h[d.z >> 7], 1);
            atomicAdd(&h[d.w >> 7], 1);
        } else {
            for (int j = e; j < NEDGES; ++j) atomicAdd(&h[ei[j] >> 7], 1);
        }
    }
    __syncthreads();
    for (int i = t; i < NBUCK; i += 256)
        if (h[i]) cur[i] = atomicAdd(&bcur[i], h[i]);
    __syncthreads();
    #pragma unroll 1
    for (int it = 0; it < TILE / 1024; ++it) {
        const int e = base + it * 1024 + t * 4;
        if (e + 3 < NEDGES) {
            const int4   d = *(const int4*)(ei + e);
            const int4   s = *(const int4*)(ei + NEDGES + e);
            const float4 w = *(const float4*)(ew + e);
            int p0 = atomicAdd(&cur[d.x >> 7], 1);
            int p1 = atomicAdd(&cur[d.y >> 7], 1);
            int p2 = atomicAdd(&cur[d.z >> 7], 1);
            int p3 = atomicAdd(&cur[d.w >> 7], 1);
            binned[p0] = make_int2(((d.x & 127) << 17) | s.x, __float_as_int(w.x));
            binned[p1] = make_int2(((d.y & 127) << 17) | s.y, __float_as_int(w.y));
            binned[p2] = make_int2(((d.z & 127) << 17) | s.z, __float_as_int(w.z));
            binned[p3] = make_int2(((d.w & 127) << 17) | s.w, __float_as_int(w.w));
        } else {
            for (int j = e; j < NEDGES; ++j) {
                const int dj = ei[j];
                const int p = atomicAdd(&cur[dj >> 7], 1);
                binned[p] = make_int2(((dj & 127) << 17) | ei[NEDGES + j],
                                      __float_as_int(ew[j]));
            }
        }
    }
}

// one block per bucket: count+scan 128 dsts -> rowbeg/rowend, dst-sorted pairs
__global__ __launch_bounds__(256) void regroup_kernel(
    const int* __restrict__ bend, const int2* __restrict__ binned,
    int* __restrict__ rowbeg, int* __restrict__ rowend, int2* __restrict__ pairs)
{
    __shared__ int cnt[DPB];
    __shared__ int s[DPB];
    const int b = blockIdx.x;
    const int t = threadIdx.x;
    const int d0 = b * DPB;
    const int nd = (NNODES - d0 < DPB) ? (NNODES - d0) : DPB;
    if (t < DPB) cnt[t] = 0;
    __syncthreads();
    const int lo = b * CAP, hiE = bend[b];
    for (int idx = lo + t; idx < hiE; idx += 256)
        atomicAdd(&cnt[binned[idx].x >> 17], 1);
    __syncthreads();
    const int v = (t < DPB) ? cnt[t] : 0;
    if (t < DPB) s[t] = v;
    __syncthreads();
    for (int o = 1; o < DPB; o <<= 1) {
        const int u = (t >= o && t < DPB) ? s[t - o] : 0;
        __syncthreads();
        if (t < DPB) s[t] += u;
        __syncthreads();
    }
    if (t < nd) {
        const int beg = lo + s[t] - v;
        rowbeg[d0 + t] = beg;
        rowend[d0 + t] = lo + s[t];
        cnt[t] = beg;                     // becomes cursor
    }
    __syncthreads();
    for (int idx = lo + t; idx < hiE; idx += 256) {
        const int2 e = binned[idx];
        const int l = e.x >> 17;
        const int pos = atomicAdd(&cnt[l], 1);
        pairs[pos] = make_int2(e.x & 0x1FFFF, e.y);
    }
}

// ============ SpMM1 full-row fp16 gather (+fused ReLU): wave per dst ========
__global__ __launch_bounds__(256) void spmm1_f16_kernel(
    const int* __restrict__ rowbeg, const int* __restrict__ rowend,
    const int2* __restrict__ pairs,
    const _Float16* __restrict__ h0, _Float16* __restrict__ h1)
{
    const int dst  = blockIdx.x * 4 + (threadIdx.x >> 6);
    const int lane = threadIdx.x & 63;
    if (dst >= NNODES) return;
    const int beg = rowbeg[dst], end = rowend[dst];
    const _Float16* base = h0 + lane * 4;
    float a0[4] = {0.f, 0.f, 0.f, 0.f};
    float a1[4] = {0.f, 0.f, 0.f, 0.f};
    int j = beg;
    for (; j + 1 < end; j += 2) {
        const int2 p0 = pairs[j];
        const int2 p1 = pairs[j + 1];
        const half4 v0 = *(const half4*)(base + (size_t)p0.x * NHID);
        const half4 v1 = *(const half4*)(base + (size_t)p1.x * NHID);
        const float w0 = __int_as_float(p0.y), w1 = __int_as_float(p1.y);
        #pragma unroll
        for (int k = 0; k < 4; ++k) {
            a0[k] = fmaf((float)v0[k], w0, a0[k]);
            a1[k] = fmaf((float)v1[k], w1, a1[k]);
        }
    }
    if (j < end) {
        const int2 p0 = pairs[j];
        const half4 v0 = *(const half4*)(base + (size_t)p0.x * NHID);
        const float w0 = __int_as_float(p0.y);
        #pragma unroll
        for (int k = 0; k < 4; ++k)
            a0[k] = fmaf((float)v0[k], w0, a0[k]);
    }
    half4 o;
    o[0] = (_Float16)fmaxf(a0[0] + a1[0], 0.f);
    o[1] = (_Float16)fmaxf(a0[1] + a1[1], 0.f);
    o[2] = (_Float16)fmaxf(a0[2] + a1[2], 0.f);
    o[3] = (_Float16)fmaxf(a0[3] + a1[3], 0.f);
    *(half4*)(h1 + (size_t)dst * NHID + lane * 4) = o;
}

// ============ SpMM2 (fp16 gather) + fused log-softmax: wave per dst =========
__global__ __launch_bounds__(256) void spmm2_csr_kernel(
    const int* __restrict__ rowbeg, const int* __restrict__ rowend,
    const int2* __restrict__ pairs,
    const _Float16* __restrict__ h2, float* __restrict__ out)
{
    const int dst  = blockIdx.x * 4 + (threadIdx.x >> 6);
    const int lane = threadIdx.x & 63;
    if (dst >= NNODES) return;
    const int beg = rowbeg[dst], end = rowend[dst];
    float a0 = 0.f, a1 = 0.f;
    int j = beg;
    for (; j + 1 < end; j += 2) {
        const int2 p0 = pairs[j];
        const int2 p1 = pairs[j + 1];
        float v0 = 0.f, v1 = 0.f;
        if (lane < NCLASS) {
            v0 = (float)h2[(size_t)p0.x * NCLASS + lane];
            v1 = (float)h2[(size_t)p1.x * NCLASS + lane];
        }
        a0 = fmaf(v0, __int_as_float(p0.y), a0);
        a1 = fmaf(v1, __int_as_float(p1.y), a1);
    }
    if (j < end) {
        const int2 p0 = pairs[j];
        float v0 = 0.f;
        if (lane < NCLASS) v0 = (float)h2[(size_t)p0.x * NCLASS + lane];
        a0 = fmaf(v0, __int_as_float(p0.y), a0);
    }
    const float acc = a0 + a1;
    float val = (lane < NCLASS) ? acc : -INFINITY;
    float m = val;
    #pragma unroll
    for (int o = 32; o >= 1; o >>= 1) m = fmaxf(m, __shfl_xor(m, o));
    float ex = (lane < NCLASS) ? expf(val - m) : 0.f;
    float s = ex;
    #pragma unroll
    for (int o = 32; o >= 1; o >>= 1) s += __shfl_xor(s, o);
    if (lane < NCLASS) out[(size_t)dst * NCLASS + lane] = val - m - logf(s);
}

// ============ launch ========================================================
extern "C" void kernel_launch(void* const* d_in, const int* in_sizes, int n_in,
                              void* d_out, int out_size, void* d_ws, size_t ws_size,
                              hipStream_t stream)
{
    const float* x  = (const float*)d_in[0];
    const int*   ei = (const int*)d_in[1];   // [2,E]: dst row then src row
    const float* ew = (const float*)d_in[2];
    const float* W1 = (const float*)d_in[3];
    const float* b1 = (const float*)d_in[4];
    const float* W2 = (const float*)d_in[5];
    const float* b2 = (const float*)d_in[6];
    float* out = (float*)d_out;

    char* ws = (char*)d_ws;
    const size_t H_BYTES = (size_t)NNODES * NHID * 4;        // 102,400,000
    // layout (total ~205.7 MB, well under proven 230.8):
    //   [0, 51.2M)        h0 fp16   (h2 fp16 8MB aliases base after spmm1)
    //   [51.2M, 80.1M)    pairs     (782*4608*8 = 28,827,648 B)
    //   [102.4M, 131.3M)  binned    (alias h1 slot; dead before spmm1)
    //   [102.4M, 153.6M)  h1 fp16
    //   [204.8M, ...)     W1T (dead after gemm1) / rowbeg, rowend, bcur, W2T
    _Float16* h0 = (_Float16*)(ws);
    int2* pairs  = (int2*)(ws + 51200000);
    _Float16* h1 = (_Float16*)(ws + H_BYTES);
    int2* binned = (int2*)(ws + H_BYTES);
    char* region = ws + 2 * H_BYTES;
    _Float16* W1T = (_Float16*)(region);                     // 262,144 B
    int* rowbeg = (int*)(region);                            // 400,000 B (alias W1T)
    int* rowend = (int*)(region + 400000);                   // 400,000 B
    int* bcur   = (int*)(region + 800000);                   // 3,128 B
    _Float16* W2T = (_Float16*)(region + 803200);            // 24,576 B [48][256]
    _Float16* h2 = (_Float16*)(ws);    // 8 MB fp16, aliases h0 (dead after spmm1)

    // 1. W1T/W2T fp16 + bucket cursors; h0 = fp16(x @ W1 + b1), BK=64
    w1_init_kernel<<<(NFEAT * NHID + 255) / 256, 256, 0, stream>>>(W1, W2, W1T, W2T, bcur);
    gemm1_f16_kernel<<<(NNODES + 63) / 64, 256, 0, stream>>>(x, W1T, b1, h0);
    // 2. CSR build: fixed-capacity bucket scatter + per-bucket regroup
    bin_scatter_kernel<<<NTILE, 256, 0, stream>>>(ei, ew, bcur, binned);
    regroup_kernel<<<NBUCK, 256, 0, stream>>>(bcur, binned, rowbeg, rowend, pairs);
    // 3. h1 = fp16(relu(spmm(h0))) — full-row gather, wave per dst
    spmm1_f16_kernel<<<(NNODES + 3) / 4, 256, 0, stream>>>(rowbeg, rowend, pairs, h0, h1);
    // 4. h2 = fp16(h1 @ W2 + b2) — MFMA
    gemm2_mfma_kernel<<<(NNODES + 63) / 64, 256, 0, stream>>>(h1, W2T, b2, h2);
    // 5. out = logsoftmax(spmm(h2)) — fp16 gather
    spmm2_csr_kernel<<<(NNODES + 3) / 4, 256, 0, stream>>>(rowbeg, rowend, pairs, h2, out);
}